// Round 3
// baseline (1703.494 us; speedup 1.0000x reference)
//
#include <hip/hip_runtime.h>
#include <cmath>

typedef __bf16 bf16;
typedef bf16 bf16x4 __attribute__((ext_vector_type(4)));
typedef bf16 bf16x8 __attribute__((ext_vector_type(8)));
typedef float f32x4 __attribute__((ext_vector_type(4)));

#define T_TOK 16384
#define HD 1024
#define ID 4096
#define MAXR 51200          // 16384 shared + 2*16384 routed + 16*128 align pad
#define CHUNK 8192
#define NCHUNK 7

// ---------------- async global -> LDS (16B per lane) ----------------
__device__ __forceinline__ void async16(const void* g, void* l) {
  void* gp = (void*)g;  // drop const
  __builtin_amdgcn_global_load_lds((__attribute__((address_space(1))) void*)gp,
                                   (__attribute__((address_space(3))) void*)l,
                                   16, 0, 0);
}

// ---------------- cast hidden_states fp32 -> bf16 ----------------
__global__ __launch_bounds__(256)
void cast_x_kernel(const float* __restrict__ X, bf16* __restrict__ Xb) {
  const int i = (blockIdx.x * 256 + threadIdx.x) * 4;
  const float4 v = *(const float4*)(X + i);
  bf16x4 o;
  o.x = (bf16)v.x; o.y = (bf16)v.y; o.z = (bf16)v.z; o.w = (bf16)v.w;
  *(bf16x4*)(Xb + i) = o;
}

// ------------- transpose + cast weights: [9][R][C] f32 -> [9][C][R] bf16 -------------
__global__ __launch_bounds__(256)
void transpose_cast(const float* __restrict__ srcR, const float* __restrict__ srcS,
                    bf16* __restrict__ dst, int R, int C) {
  const int e = blockIdx.z;
  const float* src = (e < 8) ? srcR + (size_t)e * R * C : srcS;
  __shared__ float tile[32][33];
  const int c0 = blockIdx.x * 32, r0 = blockIdx.y * 32;
  const int tx = threadIdx.x & 31, ty = threadIdx.x >> 5;
#pragma unroll
  for (int i = 0; i < 32; i += 8)
    tile[ty + i][tx] = src[(size_t)(r0 + ty + i) * C + c0 + tx];
  __syncthreads();
  bf16* d = dst + (size_t)e * R * C;
#pragma unroll
  for (int i = 0; i < 32; i += 8)
    d[(size_t)(c0 + ty + i) * R + r0 + tx] = (bf16)tile[tx][ty + i];
}

// ---------------- router: logits, top-2, renorm weights (NO atomics) ----------------
__global__ __launch_bounds__(1024)
void router_kernel(const float* __restrict__ X, const float* __restrict__ Wr,
                   int* __restrict__ topk_idx, float* __restrict__ topk_w) {
  __shared__ float W[1024 * 9];  // pad stride 9 to dodge bank conflicts
  for (int i = threadIdx.x; i < 1024 * 8; i += 1024)
    W[(i >> 3) * 9 + (i & 7)] = Wr[i];
  __syncthreads();
  const int wave = threadIdx.x >> 6, lane = threadIdx.x & 63;
  const int t = blockIdx.x * 16 + wave;
  const float* xr = X + (size_t)t * HD;
  float acc[8] = {0.f, 0.f, 0.f, 0.f, 0.f, 0.f, 0.f, 0.f};
  for (int j = 0; j < 16; ++j) {
    const float x = xr[lane + j * 64];
    const float* wp = &W[(lane + j * 64) * 9];
#pragma unroll
    for (int e2 = 0; e2 < 8; ++e2) acc[e2] += x * wp[e2];
  }
#pragma unroll
  for (int off = 32; off; off >>= 1)
#pragma unroll
    for (int e2 = 0; e2 < 8; ++e2) acc[e2] += __shfl_down(acc[e2], off);
  if (lane == 0) {
    int i0 = 0; float m0 = acc[0];
#pragma unroll
    for (int e2 = 1; e2 < 8; ++e2) if (acc[e2] > m0) { m0 = acc[e2]; i0 = e2; }
    int i1 = -1; float m1 = -3.4e38f;
#pragma unroll
    for (int e2 = 0; e2 < 8; ++e2)
      if (e2 != i0 && acc[e2] > m1) { m1 = acc[e2]; i1 = e2; }
    // renormalized top-2 softmax weights: p0/(p0+p1) = sigmoid(l0-l1)
    const float w0 = 1.f / (1.f + __expf(m1 - m0));
    topk_idx[2 * t] = i0;  topk_idx[2 * t + 1] = i1;
    topk_w[2 * t] = w0;    topk_w[2 * t + 1] = 1.f - w0;
  }
}

// ------- stable scatter into 128-aligned (expert,slot) segments -------
// Layout: rows [0,16384) shared | slot-0 segments e=0..7 | slot-1 segments e=0..7.
// Within each region every token appears exactly once -> down-GEMM RMW is race-free
// (chunk dispatches serialize), except the single chunk straddling the slot0/slot1
// boundary (meta[1]), which uses atomics.
__global__ __launch_bounds__(256)
void scatter_kernel(const int* __restrict__ topk_idx, const float* __restrict__ topk_w,
                    int* __restrict__ row_token, float* __restrict__ row_w,
                    int* __restrict__ row_exp, int* __restrict__ meta) {
  const int b = blockIdx.x;
  const int tid = threadIdx.x;
  __shared__ int hist[16];  // [s*8+e]
  if (tid < 16) hist[tid] = 0;
  __syncthreads();
  for (int t = tid; t < T_TOK; t += 256) {
    atomicAdd(&hist[topk_idx[2 * t]], 1);
    atomicAdd(&hist[8 + topk_idx[2 * t + 1]], 1);
  }
  __syncthreads();

  if (b == 16) {  // shared-expert segment: rows [0,16384), weight 1
    for (int r = tid; r < T_TOK; r += 256) {
      row_token[r] = r; row_w[r] = 1.f; row_exp[r] = 8;
    }
    if (tid == 0) {
      int tot = T_TOK;
      for (int i = 0; i < 16; ++i) tot += (hist[i] + 127) & ~127;
      meta[0] = tot;
      int b1 = T_TOK;
      for (int i = 0; i < 8; ++i) b1 += (hist[i] + 127) & ~127;
      meta[1] = b1;  // start of slot-1 region
    }
    return;
  }

  const int e = b & 7, s = b >> 3;
  const int idx = s * 8 + e;
  int base = T_TOK;
  for (int i = 0; i < idx; ++i) base += (hist[i] + 127) & ~127;
  const int cnt = hist[idx];
  const int pc = (cnt + 127) & ~127;

  __shared__ int wsum[4];
  const int wv = tid >> 6, ln = tid & 63;
  int written = 0;
  for (int c = 0; c < T_TOK / 256; ++c) {
    const int t = c * 256 + tid;
    const int hit = (topk_idx[2 * t + s] == e);
    const unsigned long long m = __ballot(hit);
    if (ln == 0) wsum[wv] = (int)__popcll(m);
    __syncthreads();
    int off = written;
    for (int i = 0; i < wv; ++i) off += wsum[i];
    if (hit) {
      const int rank = (int)__popcll(m & ((1ULL << ln) - 1ULL));  // exclusive in-wave
      const int pos = base + off + rank;
      row_token[pos] = t;
      row_w[pos] = topk_w[2 * t + s];
      row_exp[pos] = e;
    }
    written += wsum[0] + wsum[1] + wsum[2] + wsum[3];
    __syncthreads();  // wsum reused next chunk
  }
  for (int p = written + tid; p < pc; p += 256) {  // padding rows
    row_token[base + p] = 0; row_w[base + p] = 0.f; row_exp[base + p] = e;
  }
}

// ---------------- grouped GEMM, 128x128 tile, BK=32, 4 waves ----------------
// MODE 0 (up):  A = Xbf gathered via row_token [*,1024]; C = silu -> act bf16 [CHUNK,4096]
// MODE 1 (down):A = act [CHUNK,4096]; shared: store; routed: RMW (atomic only in the
//               chunk straddling the slot0/slot1 boundary)
template <int MODE, int N, int K>
__global__ __launch_bounds__(256)
void gemm_tile(const bf16* __restrict__ A0, const bf16* __restrict__ WT,
               bf16* __restrict__ act, float* __restrict__ out,
               const int* __restrict__ row_token, const float* __restrict__ row_w,
               const int* __restrict__ row_exp, const int* __restrict__ meta,
               int chunk_base) {
  const int total = meta[0];

  // XCD-aware bijective swizzle (nwg % 8 == 0 for both launches)
  const int gx = gridDim.x;
  const int nwg = gx * gridDim.y;
  int id = blockIdx.y * gx + blockIdx.x;
  id = (id & 7) * (nwg >> 3) + (id >> 3);
  const int bx = id % gx;
  const int by = id / gx;

  const int r0 = chunk_base + by * 128;
  if (r0 >= total) return;
  const int n0 = bx * 128;

  __shared__ __align__(16) bf16 As[128 * 32];
  __shared__ __align__(16) bf16 Bs[128 * 32];

  const int tid = threadIdx.x;
  const int wave = tid >> 6;
  const int lane = tid & 63;

  const int e = row_exp[r0];  // uniform across the 128-aligned block
  const bf16* W = WT + (size_t)e * N * K;

  // staging: chunk c covers LDS bytes [16c,16c+16) = row c>>2, k (c&3)*8..+8
  const int c0 = wave * 64 + lane;
  const int c1 = (4 + wave) * 64 + lane;
  const int ar0 = c0 >> 2, ar1 = c1 >> 2;
  const int ak0 = (c0 & 3) * 8, ak1 = (c1 & 3) * 8;

  const bf16 *ga0, *ga1;
  if (MODE == 0) {
    ga0 = A0 + (size_t)row_token[r0 + ar0] * K + ak0;
    ga1 = A0 + (size_t)row_token[r0 + ar1] * K + ak1;
  } else {
    const int lr0 = r0 - chunk_base;
    ga0 = A0 + (size_t)(lr0 + ar0) * K + ak0;
    ga1 = A0 + (size_t)(lr0 + ar1) * K + ak1;
  }
  const bf16* gb0 = W + (size_t)(n0 + ar0) * K + ak0;
  const bf16* gb1 = W + (size_t)(n0 + ar1) * K + ak1;

  char* AsB = (char*)As;
  char* BsB = (char*)Bs;
  char* la0 = AsB + wave * 1024;
  char* la1 = AsB + (4 + wave) * 1024;
  char* lb0 = BsB + wave * 1024;
  char* lb1 = BsB + (4 + wave) * 1024;

  f32x4 acc[4][4] = {};

  const int wm = (wave >> 1) * 64;
  const int wn = (wave & 1) * 64;
  const int lrow = lane & 15;
  const int kg = lane >> 4;

  for (int k0 = 0; k0 < K; k0 += 32) {
    async16(ga0 + k0, la0);
    async16(ga1 + k0, la1);
    async16(gb0 + k0, lb0);
    async16(gb1 + k0, lb1);
    __syncthreads();  // drains vmcnt before any wave reads LDS
    bf16x8 af[4], bb[4];
#pragma unroll
    for (int m = 0; m < 4; ++m)
      af[m] = *(const bf16x8*)&As[(wm + m * 16 + lrow) * 32 + kg * 8];
#pragma unroll
    for (int n = 0; n < 4; ++n)
      bb[n] = *(const bf16x8*)&Bs[(wn + n * 16 + lrow) * 32 + kg * 8];
#pragma unroll
    for (int m = 0; m < 4; ++m)
#pragma unroll
      for (int n = 0; n < 4; ++n)
        acc[m][n] = __builtin_amdgcn_mfma_f32_16x16x32_bf16(af[m], bb[n], acc[m][n], 0, 0, 0);
    __syncthreads();  // protect LDS from next iteration's staging
  }

  // D layout (m89): col = lane&15, row = (lane>>4)*4 + reg
  if (MODE == 0) {
    const int lr = r0 - chunk_base;
#pragma unroll
    for (int m = 0; m < 4; ++m) {
#pragma unroll
      for (int r = 0; r < 4; ++r) {
        const int row = lr + wm + m * 16 + kg * 4 + r;
        bf16* ap = act + (size_t)row * ID + n0 + wn + lrow;
#pragma unroll
        for (int n = 0; n < 4; ++n) {
          const float x = acc[m][n][r];
          const float s = x / (1.f + __expf(-x));
          ap[n * 16] = (bf16)s;
        }
      }
    }
  } else if (e == 8) {
    // shared-expert rows own their tokens exclusively and run first:
    // plain store, covers ALL of out (no memset needed).
#pragma unroll
    for (int m = 0; m < 4; ++m) {
#pragma unroll
      for (int r = 0; r < 4; ++r) {
        const int row = r0 + wm + m * 16 + kg * 4 + r;
        const int tok = row_token[row];
        float* op = out + (size_t)tok * HD + n0 + wn + lrow;
#pragma unroll
        for (int n = 0; n < 4; ++n)
          op[n * 16] = acc[m][n][r];
      }
    }
  } else {
    // routed rows: within a region each token appears exactly once, and chunk
    // dispatches serialize -> plain RMW is race-free, EXCEPT in the chunk that
    // contains the slot0/slot1 boundary (both rows of one token may co-reside).
    const int b1 = meta[1];
    const bool use_atomic = (chunk_base < b1) && (b1 < chunk_base + CHUNK);
#pragma unroll
    for (int m = 0; m < 4; ++m) {
#pragma unroll
      for (int r = 0; r < 4; ++r) {
        const int row = r0 + wm + m * 16 + kg * 4 + r;
        const float w = row_w[row];
        if (w == 0.f) continue;  // padding rows
        const int tok = row_token[row];
        float* op = out + (size_t)tok * HD + n0 + wn + lrow;
        if (use_atomic) {
#pragma unroll
          for (int n = 0; n < 4; ++n)
            atomicAdd(&op[n * 16], w * acc[m][n][r]);
        } else {
#pragma unroll
          for (int n = 0; n < 4; ++n)
            op[n * 16] = op[n * 16] + w * acc[m][n][r];
        }
      }
    }
  }
}

// ---------------- launcher ----------------
extern "C" void kernel_launch(void* const* d_in, const int* in_sizes, int n_in,
                              void* d_out, int out_size, void* d_ws, size_t ws_size,
                              hipStream_t stream) {
  const float* X   = (const float*)d_in[0];  // [4,4096,1024]
  const float* w1s = (const float*)d_in[1];  // [1024,4096]
  const float* w2s = (const float*)d_in[2];  // [4096,1024]
  const float* w1r = (const float*)d_in[3];  // [8,1024,4096]
  const float* w2r = (const float*)d_in[4];  // [8,4096,1024]
  const float* wr  = (const float*)d_in[5];  // [1024,8]
  float* out = (float*)d_out;                // [16777216]

  char* ws = (char*)d_ws;
  bf16* W1T      = (bf16*)(ws + 0);            // [9][4096][1024] bf16  75497472 B
  bf16* W2T      = (bf16*)(ws + 75497472);     // [9][1024][4096] bf16  75497472 B
  bf16* Xbf      = (bf16*)(ws + 150994944);    // [16384][1024] bf16    33554432 B
  bf16* act      = (bf16*)(ws + 184549376);    // [8192][4096] bf16     67108864 B
  int* topk_idx  = (int*)(ws + 251658240);     // [16384][2]
  float* topk_w  = (float*)(ws + 251789312);   // [16384][2]
  int* row_token = (int*)(ws + 251920384);     // [MAXR]
  float* row_w   = (float*)(ws + 252125184);   // [MAXR]
  int* row_exp   = (int*)(ws + 252329984);     // [MAXR]
  int* meta      = (int*)(ws + 252534784);     // meta[0]=total rows, meta[1]=slot1 base

  cast_x_kernel<<<T_TOK * HD / (256 * 4), 256, 0, stream>>>(X, Xbf);
  transpose_cast<<<dim3(128, 32, 9), 256, 0, stream>>>(w1r, w1s, W1T, HD, ID);
  transpose_cast<<<dim3(32, 128, 9), 256, 0, stream>>>(w2r, w2s, W2T, ID, HD);
  router_kernel<<<T_TOK / 16, 1024, 0, stream>>>(X, wr, topk_idx, topk_w);
  scatter_kernel<<<17, 256, 0, stream>>>(topk_idx, topk_w, row_token, row_w,
                                         row_exp, meta);

  for (int c = 0; c < NCHUNK; ++c) {
    gemm_tile<0, ID, HD><<<dim3(ID / 128, CHUNK / 128), 256, 0, stream>>>(
        Xbf, W1T, act, nullptr, row_token, row_w, row_exp, meta, c * CHUNK);
    gemm_tile<1, HD, ID><<<dim3(HD / 128, CHUNK / 128), 256, 0, stream>>>(
        act, W2T, nullptr, out, row_token, row_w, row_exp, meta, c * CHUNK);
  }
}

// Round 4
// 1498.594 us; speedup vs baseline: 1.1367x; 1.1367x over previous
//
#include <hip/hip_runtime.h>
#include <cmath>

typedef __bf16 bf16;
typedef bf16 bf16x4 __attribute__((ext_vector_type(4)));
typedef bf16 bf16x8 __attribute__((ext_vector_type(8)));
typedef float f32x4 __attribute__((ext_vector_type(4)));

#define T_TOK 16384
#define HD 1024
#define ID 4096
#define MAXR 50176          // 16384 shared + 32768 routed + 8*128 align pad

// ---------------- async global -> LDS (16B per lane) ----------------
__device__ __forceinline__ void async16(const void* g, void* l) {
  void* gp = (void*)g;  // drop const
  __builtin_amdgcn_global_load_lds((__attribute__((address_space(1))) void*)gp,
                                   (__attribute__((address_space(3))) void*)l,
                                   16, 0, 0);
}

// ---------------- cast hidden_states fp32 -> bf16 ----------------
__global__ __launch_bounds__(256)
void cast_x_kernel(const float* __restrict__ X, bf16* __restrict__ Xb) {
  const int i = (blockIdx.x * 256 + threadIdx.x) * 4;
  const float4 v = *(const float4*)(X + i);
  bf16x4 o;
  o.x = (bf16)v.x; o.y = (bf16)v.y; o.z = (bf16)v.z; o.w = (bf16)v.w;
  *(bf16x4*)(Xb + i) = o;
}

// ------------- transpose + cast weights: [9][R][C] f32 -> [9][C][R] bf16 -------------
__global__ __launch_bounds__(256)
void transpose_cast(const float* __restrict__ srcR, const float* __restrict__ srcS,
                    bf16* __restrict__ dst, int R, int C) {
  const int e = blockIdx.z;
  const float* src = (e < 8) ? srcR + (size_t)e * R * C : srcS;
  __shared__ float tile[32][33];
  const int c0 = blockIdx.x * 32, r0 = blockIdx.y * 32;
  const int tx = threadIdx.x & 31, ty = threadIdx.x >> 5;
#pragma unroll
  for (int i = 0; i < 32; i += 8)
    tile[ty + i][tx] = src[(size_t)(r0 + ty + i) * C + c0 + tx];
  __syncthreads();
  bf16* d = dst + (size_t)e * R * C;
#pragma unroll
  for (int i = 0; i < 32; i += 8)
    d[(size_t)(c0 + ty + i) * R + r0 + tx] = (bf16)tile[tx][ty + i];
}

// ---------------- router: logits, top-2, renorm weights (NO atomics) ----------------
__global__ __launch_bounds__(1024)
void router_kernel(const float* __restrict__ X, const float* __restrict__ Wr,
                   int* __restrict__ topk_idx, float* __restrict__ topk_w) {
  __shared__ float W[1024 * 9];  // pad stride 9 to dodge bank conflicts
  for (int i = threadIdx.x; i < 1024 * 8; i += 1024)
    W[(i >> 3) * 9 + (i & 7)] = Wr[i];
  __syncthreads();
  const int wave = threadIdx.x >> 6, lane = threadIdx.x & 63;
  const int t = blockIdx.x * 16 + wave;
  const float* xr = X + (size_t)t * HD;
  float acc[8] = {0.f, 0.f, 0.f, 0.f, 0.f, 0.f, 0.f, 0.f};
  for (int j = 0; j < 16; ++j) {
    const float x = xr[lane + j * 64];
    const float* wp = &W[(lane + j * 64) * 9];
#pragma unroll
    for (int e2 = 0; e2 < 8; ++e2) acc[e2] += x * wp[e2];
  }
#pragma unroll
  for (int off = 32; off; off >>= 1)
#pragma unroll
    for (int e2 = 0; e2 < 8; ++e2) acc[e2] += __shfl_down(acc[e2], off);
  if (lane == 0) {
    int i0 = 0; float m0 = acc[0];
#pragma unroll
    for (int e2 = 1; e2 < 8; ++e2) if (acc[e2] > m0) { m0 = acc[e2]; i0 = e2; }
    int i1 = -1; float m1 = -3.4e38f;
#pragma unroll
    for (int e2 = 0; e2 < 8; ++e2)
      if (e2 != i0 && acc[e2] > m1) { m1 = acc[e2]; i1 = e2; }
    // renormalized top-2 softmax weights: p0/(p0+p1) = sigmoid(l0-l1)
    const float w0 = 1.f / (1.f + __expf(m1 - m0));
    topk_idx[2 * t] = i0;  topk_idx[2 * t + 1] = i1;
    topk_w[2 * t] = w0;    topk_w[2 * t + 1] = 1.f - w0;
  }
}

// ------- stable scatter into 128-aligned per-expert segments; block 8 = shared seg -------
__global__ __launch_bounds__(256)
void scatter_kernel(const int* __restrict__ topk_idx, const float* __restrict__ topk_w,
                    int* __restrict__ row_token, float* __restrict__ row_w,
                    int* __restrict__ row_exp, int* __restrict__ meta) {
  const int e = blockIdx.x;
  const int tid = threadIdx.x;
  __shared__ int hist[8];
  if (tid < 8) hist[tid] = 0;
  __syncthreads();
  for (int t = tid; t < T_TOK; t += 256) {
    atomicAdd(&hist[topk_idx[2 * t]], 1);
    atomicAdd(&hist[topk_idx[2 * t + 1]], 1);
  }
  __syncthreads();

  if (e == 8) {  // shared-expert segment: rows [0,16384), weight 1
    for (int r = tid; r < T_TOK; r += 256) {
      row_token[r] = r; row_w[r] = 1.f; row_exp[r] = 8;
    }
    if (tid == 0) {
      int tot = T_TOK;
      for (int i = 0; i < 8; ++i) tot += (hist[i] + 127) & ~127;
      meta[0] = tot;
    }
    return;
  }

  int base = T_TOK;
  for (int i = 0; i < e; ++i) base += (hist[i] + 127) & ~127;
  const int cnt = hist[e];
  const int pc = (cnt + 127) & ~127;

  __shared__ int wsum[4];
  const int wv = tid >> 6, ln = tid & 63;
  int written = 0;
  for (int c = 0; c < T_TOK / 256; ++c) {
    const int t = c * 256 + tid;
    const int i0 = topk_idx[2 * t], i1 = topk_idx[2 * t + 1];
    const int slot = (i0 == e) ? 0 : ((i1 == e) ? 1 : -1);
    const unsigned long long m = __ballot(slot >= 0);
    if (ln == 0) wsum[wv] = (int)__popcll(m);
    __syncthreads();
    int off = written;
    for (int i = 0; i < wv; ++i) off += wsum[i];
    if (slot >= 0) {
      const int rank = (int)__popcll(m & ((1ULL << ln) - 1ULL));  // exclusive in-wave
      const int pos = base + off + rank;
      row_token[pos] = t;
      row_w[pos] = topk_w[2 * t + slot];
      row_exp[pos] = e;
    }
    written += wsum[0] + wsum[1] + wsum[2] + wsum[3];
    __syncthreads();  // wsum reused next chunk
  }
  for (int p = written + tid; p < pc; p += 256) {  // padding rows
    row_token[base + p] = 0; row_w[base + p] = 0.f; row_exp[base + p] = e;
  }
}

// ---------------- grouped GEMM, 128x128 tile, BK=32, 4 waves ----------------
// MODE 0 (up):        A = Xbf gathered via row_token; C = silu -> act bf16 rows [cb..)
// MODE 1 (down-store):A = act; plain store (shared rows, each token exactly once)
// MODE 2 (down-atomic):A = act; w * val atomicAdd (routed rows)
template <int MODE, int N, int K>
__global__ __launch_bounds__(256)
void gemm_tile(const bf16* __restrict__ A0, const bf16* __restrict__ WT,
               bf16* __restrict__ act, float* __restrict__ out,
               const int* __restrict__ row_token, const float* __restrict__ row_w,
               const int* __restrict__ row_exp, const int* __restrict__ meta,
               int range_start, int chunk_base) {
  const int total = meta[0];

  // XCD-aware bijective swizzle (m204) — valid for any nwg
  const int gx = gridDim.x;
  const int nwg = gx * gridDim.y;
  int id = blockIdx.y * gx + blockIdx.x;
  {
    const int q = nwg >> 3, rm = nwg & 7;
    const int xcd = id & 7, loc = id >> 3;
    id = (xcd < rm ? xcd * (q + 1) : rm * (q + 1) + (xcd - rm) * q) + loc;
  }
  const int bx = id % gx;
  const int by = id / gx;

  const int r0 = range_start + by * 128;
  if (r0 >= total) return;
  const int n0 = bx * 128;

  __shared__ __align__(16) bf16 As[128 * 32];
  __shared__ __align__(16) bf16 Bs[128 * 32];

  const int tid = threadIdx.x;
  const int wave = tid >> 6;
  const int lane = tid & 63;

  const int e = row_exp[r0];  // uniform across the 128-aligned block
  const bf16* W = WT + (size_t)e * N * K;

  // staging: chunk c covers LDS bytes [16c,16c+16) = row c>>2, k (c&3)*8..+8
  const int c0 = wave * 64 + lane;
  const int c1 = (4 + wave) * 64 + lane;
  const int ar0 = c0 >> 2, ar1 = c1 >> 2;
  const int ak0 = (c0 & 3) * 8, ak1 = (c1 & 3) * 8;

  const bf16 *ga0, *ga1;
  if (MODE == 0) {
    ga0 = A0 + (size_t)row_token[r0 + ar0] * K + ak0;
    ga1 = A0 + (size_t)row_token[r0 + ar1] * K + ak1;
  } else {
    const int lr0 = r0 - chunk_base;
    ga0 = A0 + (size_t)(lr0 + ar0) * K + ak0;
    ga1 = A0 + (size_t)(lr0 + ar1) * K + ak1;
  }
  const bf16* gb0 = W + (size_t)(n0 + ar0) * K + ak0;
  const bf16* gb1 = W + (size_t)(n0 + ar1) * K + ak1;

  char* AsB = (char*)As;
  char* BsB = (char*)Bs;
  char* la0 = AsB + wave * 1024;
  char* la1 = AsB + (4 + wave) * 1024;
  char* lb0 = BsB + wave * 1024;
  char* lb1 = BsB + (4 + wave) * 1024;

  f32x4 acc[4][4] = {};

  const int wm = (wave >> 1) * 64;
  const int wn = (wave & 1) * 64;
  const int lrow = lane & 15;
  const int kg = lane >> 4;

  for (int k0 = 0; k0 < K; k0 += 32) {
    async16(ga0 + k0, la0);
    async16(ga1 + k0, la1);
    async16(gb0 + k0, lb0);
    async16(gb1 + k0, lb1);
    __syncthreads();  // drains vmcnt before any wave reads LDS
    bf16x8 af[4], bb[4];
#pragma unroll
    for (int m = 0; m < 4; ++m)
      af[m] = *(const bf16x8*)&As[(wm + m * 16 + lrow) * 32 + kg * 8];
#pragma unroll
    for (int n = 0; n < 4; ++n)
      bb[n] = *(const bf16x8*)&Bs[(wn + n * 16 + lrow) * 32 + kg * 8];
#pragma unroll
    for (int m = 0; m < 4; ++m)
#pragma unroll
      for (int n = 0; n < 4; ++n)
        acc[m][n] = __builtin_amdgcn_mfma_f32_16x16x32_bf16(af[m], bb[n], acc[m][n], 0, 0, 0);
    __syncthreads();  // protect LDS from next iteration's staging
  }

  // D layout (m89): col = lane&15, row = (lane>>4)*4 + reg
  if (MODE == 0) {
#pragma unroll
    for (int m = 0; m < 4; ++m) {
#pragma unroll
      for (int r = 0; r < 4; ++r) {
        const int row = (r0 - chunk_base) + wm + m * 16 + kg * 4 + r;
        bf16* ap = act + (size_t)row * ID + n0 + wn + lrow;
#pragma unroll
        for (int n = 0; n < 4; ++n) {
          const float x = acc[m][n][r];
          const float s = x / (1.f + __expf(-x));
          ap[n * 16] = (bf16)s;
        }
      }
    }
  } else if (MODE == 1) {
    // shared-expert rows own their tokens exclusively and this dispatch runs
    // before any routed dispatch: plain store, covers ALL of out.
#pragma unroll
    for (int m = 0; m < 4; ++m) {
#pragma unroll
      for (int r = 0; r < 4; ++r) {
        const int row = r0 + wm + m * 16 + kg * 4 + r;
        const int tok = row_token[row];
        float* op = out + (size_t)tok * HD + n0 + wn + lrow;
#pragma unroll
        for (int n = 0; n < 4; ++n)
          op[n * 16] = acc[m][n][r];
      }
    }
  } else {
#pragma unroll
    for (int m = 0; m < 4; ++m) {
#pragma unroll
      for (int r = 0; r < 4; ++r) {
        const int row = r0 + wm + m * 16 + kg * 4 + r;
        const float w = row_w[row];
        if (w == 0.f) continue;  // padding rows
        const int tok = row_token[row];
        float* op = out + (size_t)tok * HD + n0 + wn + lrow;
#pragma unroll
        for (int n = 0; n < 4; ++n)
          atomicAdd(&op[n * 16], w * acc[m][n][r]);
      }
    }
  }
}

// ---------------- launcher ----------------
extern "C" void kernel_launch(void* const* d_in, const int* in_sizes, int n_in,
                              void* d_out, int out_size, void* d_ws, size_t ws_size,
                              hipStream_t stream) {
  const float* X   = (const float*)d_in[0];  // [4,4096,1024]
  const float* w1s = (const float*)d_in[1];  // [1024,4096]
  const float* w2s = (const float*)d_in[2];  // [4096,1024]
  const float* w1r = (const float*)d_in[3];  // [8,1024,4096]
  const float* w2r = (const float*)d_in[4];  // [8,4096,1024]
  const float* wr  = (const float*)d_in[5];  // [1024,8]
  float* out = (float*)d_out;                // [16777216]

  char* ws = (char*)d_ws;
  bf16* W1T      = (bf16*)(ws + 0);            // [9][4096][1024] bf16  75497472 B
  bf16* W2T      = (bf16*)(ws + 75497472);     // [9][1024][4096] bf16  75497472 B
  bf16* Xbf      = (bf16*)(ws + 150994944);    // [16384][1024] bf16    33554432 B
  int* topk_idx  = (int*)(ws + 184549376);     // 131072 B
  float* topk_w  = (float*)(ws + 184680448);   // 131072 B
  int* row_token = (int*)(ws + 184811520);     // 200704 B
  float* row_w   = (float*)(ws + 185012224);   // 200704 B
  int* row_exp   = (int*)(ws + 185212928);     // 200704 B
  int* meta      = (int*)(ws + 185413632);     // 256 B
  bf16* act      = (bf16*)(ws + 185413888);    // adaptive: Rc rows x 4096 bf16

  // Adaptive chunk rows: as many 128-row tiles as the workspace allows.
  const size_t avail = ws_size - 185413888ULL;
  long long rc = (long long)(avail / (ID * 2));  // rows that fit
  if (rc > MAXR) rc = MAXR;
  rc &= ~127LL;
  const int Rc = (int)rc;  // guaranteed >= 8192 given ws_size >= ~253 MB

  cast_x_kernel<<<T_TOK * HD / (256 * 4), 256, 0, stream>>>(X, Xbf);
  transpose_cast<<<dim3(128, 32, 9), 256, 0, stream>>>(w1r, w1s, W1T, HD, ID);
  transpose_cast<<<dim3(32, 128, 9), 256, 0, stream>>>(w2r, w2s, W2T, ID, HD);
  router_kernel<<<T_TOK / 16, 1024, 0, stream>>>(X, wr, topk_idx, topk_w);
  scatter_kernel<<<9, 256, 0, stream>>>(topk_idx, topk_w, row_token, row_w,
                                        row_exp, meta);

  for (int cb = 0; cb < MAXR; cb += Rc) {
    const int ce = (cb + Rc < MAXR) ? cb + Rc : MAXR;
    // up-projection for rows [cb, ce) -> act[0 .. ce-cb)
    gemm_tile<0, ID, HD><<<dim3(ID / 128, (ce - cb) / 128), 256, 0, stream>>>(
        Xbf, W1T, act, nullptr, row_token, row_w, row_exp, meta, cb, cb);
    // down-projection, shared part (plain store) then routed part (atomic);
    // dispatches serialize on the stream so store-then-atomic is race-free.
    const int s_end = (ce < T_TOK) ? ce : T_TOK;
    if (cb < s_end) {
      gemm_tile<1, HD, ID><<<dim3(HD / 128, (s_end - cb) / 128), 256, 0, stream>>>(
          act, W2T, nullptr, out, row_token, row_w, row_exp, meta, cb, cb);
    }
    const int r_start = (cb > T_TOK) ? cb : T_TOK;
    if (r_start < ce) {
      gemm_tile<2, HD, ID><<<dim3(HD / 128, (ce - r_start) / 128), 256, 0, stream>>>(
          act, W2T, nullptr, out, row_token, row_w, row_exp, meta, r_start, cb);
    }
  }
}